// Round 1
// baseline (1209.784 us; speedup 1.0000x reference)
//
#include <hip/hip_runtime.h>

#define N_NODES 100000
#define OUT_CH  128
#define N_EDGES 625000

typedef short short8 __attribute__((ext_vector_type(8)));
typedef float f32x4  __attribute__((ext_vector_type(4)));

__device__ inline short f32_bf16(float f) {
    union { float f; unsigned u; } c{f};
    unsigned r = 0x7FFFu + ((c.u >> 16) & 1u);
    return (short)((c.u + r) >> 16);
}

// Build B fragments (both heads fused: cols 0..127 = loc_w, 128..255 = std_w)
// Bfrag[ks][nt][lane] = 8 bf16: B[k][c] = W'[c][k], c = nt*16+(lane&15),
// k = ks*32+(lane>>4)*8+j  -> exactly the mfma_f32_16x16x32_bf16 B layout.
__global__ void prep_b(const float* __restrict__ lw, const float* __restrict__ sw,
                       short8* __restrict__ B) {
    int g = blockIdx.x * blockDim.x + threadIdx.x;   // 4096 threads total
    int lane = g & 63, nt = (g >> 6) & 15, ks = g >> 10;
    int c = nt * 16 + (lane & 15);
    int k = ks * 32 + (lane >> 4) * 8;
    const float* src = (c < OUT_CH) ? (lw + c * OUT_CH + k)
                                    : (sw + (c - OUT_CH) * OUT_CH + k);
    short8 o;
#pragma unroll
    for (int j = 0; j < 8; ++j) o[j] = f32_bf16(src[j]);
    B[(ks * 16 + nt) * 64 + lane] = o;
}

// message = emb[s]*norm, scatter-add into ptr (= d_out loc region, pre-zeroed)
__global__ void scatter_k(const float* __restrict__ emb, const int* __restrict__ ei,
                          const float* __restrict__ en, float* __restrict__ out) {
    int idx = blockIdx.x * blockDim.x + threadIdx.x;  // E*32 threads
    int e = idx >> 5, q = idx & 31;
    int s = ei[e], t = ei[N_EDGES + e];
    float nm = en[e];
    float4 v = *(const float4*)(emb + (size_t)s * OUT_CH + q * 4);
    float* dst = out + (size_t)t * OUT_CH + q * 4;
    atomicAdd(dst + 0, v.x * nm);
    atomicAdd(dst + 1, v.y * nm);
    atomicAdd(dst + 2, v.z * nm);
    atomicAdd(dst + 3, v.w * nm);
}

// Fused loc/std GEMM: [100K,128] x [128,256] bf16 MFMA, in-place over ptr.
// Each wave owns 16 rows; reads its rows fully (K-loop) before overwriting.
__global__ __launch_bounds__(256) void gemm_k(float* __restrict__ out,
                                              const short8* __restrict__ B,
                                              const float* __restrict__ lb,
                                              const float* __restrict__ sb) {
    int tid = threadIdx.x;
    int wave = tid >> 6, lane = tid & 63;
    int n0 = (blockIdx.x * 4 + wave) * 16;
    if (n0 >= N_NODES) return;

    const float* P = out;                                  // ptr lives in loc region
    float* loc  = out;
    float* stdo = out + (size_t)N_NODES * OUT_CH;

    int arow = n0 + (lane & 15);
    int kb = (lane >> 4) * 8;

    f32x4 acc[16];
#pragma unroll
    for (int i = 0; i < 16; ++i) acc[i] = (f32x4)(0.f);

#pragma unroll
    for (int ks = 0; ks < 4; ++ks) {
        const float* ap = P + (size_t)arow * OUT_CH + ks * 32 + kb;
        float4 a0 = *(const float4*)ap;
        float4 a1 = *(const float4*)(ap + 4);
        short8 a;
        a[0] = f32_bf16(a0.x); a[1] = f32_bf16(a0.y);
        a[2] = f32_bf16(a0.z); a[3] = f32_bf16(a0.w);
        a[4] = f32_bf16(a1.x); a[5] = f32_bf16(a1.y);
        a[6] = f32_bf16(a1.z); a[7] = f32_bf16(a1.w);
#pragma unroll
        for (int nt = 0; nt < 16; ++nt) {
            short8 b = B[(ks * 16 + nt) * 64 + lane];
            acc[nt] = __builtin_amdgcn_mfma_f32_16x16x32_bf16(a, b, acc[nt], 0, 0, 0);
        }
    }

    int col = lane & 15, r0 = (lane >> 4) * 4;
#pragma unroll
    for (int nt = 0; nt < 16; ++nt) {
        int c = nt * 16 + col;
        if (c < OUT_CH) {
            float bias = lb[c];
#pragma unroll
            for (int r = 0; r < 4; ++r)
                loc[(size_t)(n0 + r0 + r) * OUT_CH + c] = acc[nt][r] + bias;
        } else {
            int cc = c - OUT_CH;
            float bias = sb[cc];
#pragma unroll
            for (int r = 0; r < 4; ++r) {
                float x = acc[nt][r] + bias;
                float sp = fmaxf(x, 0.f) + log1pf(expf(-fabsf(x)));
                stdo[(size_t)(n0 + r0 + r) * OUT_CH + cc] = sp + 1e-10f;
            }
        }
    }
}

// logits[e] = dot(z[s], z[t]), 32 lanes per edge, z = loc (f32)
__global__ void logits_k(const float* __restrict__ z, const int* __restrict__ ei,
                         float* __restrict__ lg) {
    int idx = blockIdx.x * blockDim.x + threadIdx.x;  // E*32 threads
    int e = idx >> 5, q = idx & 31;
    if (e >= N_EDGES) return;
    int s = ei[e], t = ei[N_EDGES + e];
    float4 a = *(const float4*)(z + (size_t)s * OUT_CH + q * 4);
    float4 b = *(const float4*)(z + (size_t)t * OUT_CH + q * 4);
    float d = a.x * b.x + a.y * b.y + a.z * b.z + a.w * b.w;
#pragma unroll
    for (int m = 16; m >= 1; m >>= 1) d += __shfl_xor(d, m);
    if (q == 0) lg[e] = d;
}

extern "C" void kernel_launch(void* const* d_in, const int* in_sizes, int n_in,
                              void* d_out, int out_size, void* d_ws, size_t ws_size,
                              hipStream_t stream) {
    const float* emb = (const float*)d_in[0];
    const int*   ei  = (const int*)d_in[1];      // edge_index delivered as int32
    const float* en  = (const float*)d_in[2];
    const float* lw  = (const float*)d_in[3];
    const float* lb  = (const float*)d_in[4];
    const float* sw  = (const float*)d_in[5];
    const float* sb  = (const float*)d_in[6];
    float* out = (float*)d_out;
    short8* B = (short8*)d_ws;                   // 64 KB fragment-ordered weights

    // zero the accumulation region (loc rows double as ptr accumulator)
    hipMemsetAsync(out, 0, (size_t)N_NODES * OUT_CH * sizeof(float), stream);

    prep_b<<<16, 256, 0, stream>>>(lw, sw, B);
    scatter_k<<<(N_EDGES * 32) / 256, 256, 0, stream>>>(emb, ei, en, out);
    gemm_k<<<(N_NODES / 16 + 3) / 4, 256, 0, stream>>>(out, B, lb, sb);
    logits_k<<<(N_EDGES * 32) / 256, 256, 0, stream>>>(
        out, ei, out + (size_t)2 * N_NODES * OUT_CH);
}

// Round 2
// 303.652 us; speedup vs baseline: 3.9841x; 3.9841x over previous
//
#include <hip/hip_runtime.h>

#define N_NODES 100000
#define OUT_CH  128
#define N_EDGES 625000

typedef short short8 __attribute__((ext_vector_type(8)));
typedef float f32x4  __attribute__((ext_vector_type(4)));

__device__ inline short f32_bf16(float f) {
    union { float f; unsigned u; } c{f};
    unsigned r = 0x7FFFu + ((c.u >> 16) & 1u);
    return (short)((c.u + r) >> 16);
}

// ---- B fragments (loc_w | std_w fused, mfma_f32_16x16x32_bf16 B layout) ----
__global__ void prep_b(const float* __restrict__ lw, const float* __restrict__ sw,
                       short8* __restrict__ B) {
    int g = blockIdx.x * blockDim.x + threadIdx.x;   // 4096 threads
    int lane = g & 63, nt = (g >> 6) & 15, ks = g >> 10;
    int c = nt * 16 + (lane & 15);
    int k = ks * 32 + (lane >> 4) * 8;
    const float* src = (c < OUT_CH) ? (lw + c * OUT_CH + k)
                                    : (sw + (c - OUT_CH) * OUT_CH + k);
    short8 o;
#pragma unroll
    for (int j = 0; j < 8; ++j) o[j] = f32_bf16(src[j]);
    B[(ks * 16 + nt) * 64 + lane] = o;
}

// ---- counting sort of edges by target node ----
__global__ void hist_k(const int* __restrict__ ei, int* __restrict__ counts) {
    int e = blockIdx.x * blockDim.x + threadIdx.x;
    if (e < N_EDGES) atomicAdd(&counts[ei[N_EDGES + e]], 1);
}

__global__ void scan1_k(const int* __restrict__ counts, int* __restrict__ offsets,
                        int* __restrict__ partials) {
    __shared__ int lds[1024];
    int tid = threadIdx.x;
    int e = blockIdx.x * 1024 + tid;
    int v = (e < N_NODES) ? counts[e] : 0;
    lds[tid] = v;
    __syncthreads();
    for (int off = 1; off < 1024; off <<= 1) {
        int t = (tid >= off) ? lds[tid - off] : 0;
        __syncthreads();
        lds[tid] += t;
        __syncthreads();
    }
    int incl = lds[tid];
    if (e < N_NODES) offsets[e] = incl - v;      // exclusive within block
    if (tid == 1023) partials[blockIdx.x] = incl;
}

__global__ void scan2_k(int* __restrict__ partials, int nb, int* __restrict__ offsets) {
    if (threadIdx.x == 0 && blockIdx.x == 0) {
        int run = 0;
        for (int i = 0; i < nb; ++i) { int c = partials[i]; partials[i] = run; run += c; }
        offsets[N_NODES] = N_EDGES;              // end sentinel
    }
}

__global__ void scan3_k(int* __restrict__ offsets, const int* __restrict__ partials) {
    int e = blockIdx.x * 1024 + threadIdx.x;
    if (e < N_NODES) offsets[e] += partials[blockIdx.x];
}

__global__ void reorder_k(const int* __restrict__ ei, const float* __restrict__ en,
                          const int* __restrict__ offsets, int* __restrict__ cursors,
                          int2* __restrict__ pairs) {
    int e = blockIdx.x * blockDim.x + threadIdx.x;
    if (e >= N_EDGES) return;
    int t = ei[N_EDGES + e];
    int pos = offsets[t] + atomicAdd(&cursors[t], 1);
    int2 p; p.x = ei[e]; p.y = __float_as_int(en[e]);
    pairs[pos] = p;
}

// ---- segment-sum gather: one wave per node, float2 per lane ----
__global__ void gather_k(const float* __restrict__ emb, const int* __restrict__ offsets,
                         const int2* __restrict__ pairs, float* __restrict__ out) {
    int g = blockIdx.x * blockDim.x + threadIdx.x;
    int node = g >> 6, lane = g & 63;
    if (node >= N_NODES) return;
    int beg = offsets[node], end = offsets[node + 1];
    float ax = 0.f, ay = 0.f;
    const float2* base = (const float2*)emb;
    for (int j = beg; j < end; ++j) {
        int2 p = pairs[j];
        float nm = __int_as_float(p.y);
        float2 v = base[(size_t)p.x * 64 + lane];
        ax += v.x * nm; ay += v.y * nm;
    }
    float2 o; o.x = ax; o.y = ay;
    ((float2*)out)[(size_t)node * 64 + lane] = o;   // ptr -> loc region
}

// ---- fused loc/std GEMM: [100K,128] x [128,256] bf16 MFMA, in-place over ptr ----
__global__ __launch_bounds__(256) void gemm_k(float* __restrict__ out,
                                              const short8* __restrict__ B,
                                              const float* __restrict__ lb,
                                              const float* __restrict__ sb) {
    int tid = threadIdx.x;
    int wave = tid >> 6, lane = tid & 63;
    int n0 = (blockIdx.x * 4 + wave) * 16;
    if (n0 >= N_NODES) return;

    const float* P = out;
    float* loc  = out;
    float* stdo = out + (size_t)N_NODES * OUT_CH;

    int arow = n0 + (lane & 15);
    int kb = (lane >> 4) * 8;

    f32x4 acc[16];
#pragma unroll
    for (int i = 0; i < 16; ++i) acc[i] = (f32x4)(0.f);

#pragma unroll
    for (int ks = 0; ks < 4; ++ks) {
        const float* ap = P + (size_t)arow * OUT_CH + ks * 32 + kb;
        float4 a0 = *(const float4*)ap;
        float4 a1 = *(const float4*)(ap + 4);
        short8 a;
        a[0] = f32_bf16(a0.x); a[1] = f32_bf16(a0.y);
        a[2] = f32_bf16(a0.z); a[3] = f32_bf16(a0.w);
        a[4] = f32_bf16(a1.x); a[5] = f32_bf16(a1.y);
        a[6] = f32_bf16(a1.z); a[7] = f32_bf16(a1.w);
#pragma unroll
        for (int nt = 0; nt < 16; ++nt) {
            short8 b = B[(ks * 16 + nt) * 64 + lane];
            acc[nt] = __builtin_amdgcn_mfma_f32_16x16x32_bf16(a, b, acc[nt], 0, 0, 0);
        }
    }

    int col = lane & 15, r0 = (lane >> 4) * 4;
#pragma unroll
    for (int nt = 0; nt < 16; ++nt) {
        int c = nt * 16 + col;
        if (c < OUT_CH) {
            float bias = lb[c];
#pragma unroll
            for (int r = 0; r < 4; ++r)
                loc[(size_t)(n0 + r0 + r) * OUT_CH + c] = acc[nt][r] + bias;
        } else {
            int cc = c - OUT_CH;
            float bias = sb[cc];
#pragma unroll
            for (int r = 0; r < 4; ++r) {
                float x = acc[nt][r] + bias;
                float sp = fmaxf(x, 0.f) + log1pf(expf(-fabsf(x)));
                stdo[(size_t)(n0 + r0 + r) * OUT_CH + cc] = sp + 1e-10f;
            }
        }
    }
}

// ---- logits[e] = dot(z[s], z[t]) ----
__global__ void logits_k(const float* __restrict__ z, const int* __restrict__ ei,
                         float* __restrict__ lg) {
    int idx = blockIdx.x * blockDim.x + threadIdx.x;
    int e = idx >> 5, q = idx & 31;
    if (e >= N_EDGES) return;
    int s = ei[e], t = ei[N_EDGES + e];
    float4 a = *(const float4*)(z + (size_t)s * OUT_CH + q * 4);
    float4 b = *(const float4*)(z + (size_t)t * OUT_CH + q * 4);
    float d = a.x * b.x + a.y * b.y + a.z * b.z + a.w * b.w;
#pragma unroll
    for (int m = 16; m >= 1; m >>= 1) d += __shfl_xor(d, m);
    if (q == 0) lg[e] = d;
}

extern "C" void kernel_launch(void* const* d_in, const int* in_sizes, int n_in,
                              void* d_out, int out_size, void* d_ws, size_t ws_size,
                              hipStream_t stream) {
    const float* emb = (const float*)d_in[0];
    const int*   ei  = (const int*)d_in[1];
    const float* en  = (const float*)d_in[2];
    const float* lw  = (const float*)d_in[3];
    const float* lb  = (const float*)d_in[4];
    const float* sw  = (const float*)d_in[5];
    const float* sb  = (const float*)d_in[6];
    float* out = (float*)d_out;

    char* ws = (char*)d_ws;
    size_t o = 0;
    short8* B       = (short8*)(ws + o); o += 65536;
    int*    counts  = (int*)(ws + o);    o += 400128;
    int*    offsets = (int*)(ws + o);    o += 400128;   // N_NODES+1 entries
    int*    cursors = (int*)(ws + o);    o += 400128;
    int*    partials= (int*)(ws + o);    o += 1024;
    int2*   pairs   = (int2*)(ws + o);   o += (size_t)N_EDGES * 8;

    hipMemsetAsync(counts, 0, N_NODES * sizeof(int), stream);
    hipMemsetAsync(cursors, 0, N_NODES * sizeof(int), stream);

    prep_b<<<16, 256, 0, stream>>>(lw, sw, B);
    hist_k<<<(N_EDGES + 255) / 256, 256, 0, stream>>>(ei, counts);
    scan1_k<<<98, 1024, 0, stream>>>(counts, offsets, partials);
    scan2_k<<<1, 64, 0, stream>>>(partials, 98, offsets);
    scan3_k<<<98, 1024, 0, stream>>>(offsets, partials);
    reorder_k<<<(N_EDGES + 255) / 256, 256, 0, stream>>>(ei, en, offsets, cursors, pairs);
    gather_k<<<(N_NODES * 64 + 255) / 256, 256, 0, stream>>>(emb, offsets, pairs, out);
    gemm_k<<<(N_NODES / 16 + 3) / 4, 256, 0, stream>>>(out, B, lb, sb);
    logits_k<<<(N_EDGES * 32 + 255) / 256, 256, 0, stream>>>(
        out, ei, out + (size_t)2 * N_NODES * OUT_CH);
}